// Round 5
// baseline (156.247 us; speedup 1.0000x reference)
//
#include <hip/hip_runtime.h>

#define N_NODES 100000
#define D 128

typedef unsigned short ushort_t;
typedef __attribute__((ext_vector_type(8))) short short8;
typedef __attribute__((ext_vector_type(4))) float f32x4;

// round-to-nearest-even f32 -> bf16 bits (finite inputs)
__device__ __forceinline__ unsigned f2bf(float x) {
    unsigned u = __float_as_uint(x);
    return (u + 0x7fffu + ((u >> 16) & 1u)) >> 16;
}

// ---------------------------------------------------------------------------
// Kernel 1: W -> MFMA A-fragment-ordered bf16 (Wfrag).
// mfma_f32_16x16x32_bf16 A-frag: lane l holds row (l&15), k = (l>>4)*8+i.
// A-matrix = W tile (jt,kt): A[j][k] = W[jt*16+j][kt*32+k].
// Layout: Wfrag[((jt*4+kt)*64 + l)*8 + i]
// ---------------------------------------------------------------------------
__global__ __launch_bounds__(64)
void build_wfrag_kernel(const float* __restrict__ W,
                        ushort_t* __restrict__ Wfrag) {
    const int t  = blockIdx.x;      // 0..31 = jt*4 + kt
    const int jt = t >> 2, kt = t & 3;
    const int l  = threadIdx.x;
    const float* src = W + (size_t)(jt * 16 + (l & 15)) * D + kt * 32 + (l >> 4) * 8;
    const float4 p0 = *reinterpret_cast<const float4*>(src);
    const float4 p1 = *reinterpret_cast<const float4*>(src + 4);
    uint4 o;
    o.x = f2bf(p0.x) | (f2bf(p0.y) << 16);
    o.y = f2bf(p0.z) | (f2bf(p0.w) << 16);
    o.z = f2bf(p1.x) | (f2bf(p1.y) << 16);
    o.w = f2bf(p1.z) | (f2bf(p1.w) << 16);
    *reinterpret_cast<uint4*>(Wfrag + ((size_t)t * 64 + l) * 8) = o;
}

// ---------------------------------------------------------------------------
// Kernel 2: row_ptr[i] = lower_bound(edge_rows, i)
// ---------------------------------------------------------------------------
__global__ void build_rowptr_kernel(const int* __restrict__ rows,
                                    int* __restrict__ row_ptr, int n_edges) {
    int i = blockIdx.x * blockDim.x + threadIdx.x;
    if (i > N_NODES) return;
    int lo = 0, hi = n_edges;
    while (lo < hi) {
        int mid = (lo + hi) >> 1;
        if (rows[mid] < i) lo = mid + 1; else hi = mid;
    }
    row_ptr[i] = lo;
}

// ---------------------------------------------------------------------------
// Kernel 3: G = bf16(H @ W^T) via MFMA, stored SPLIT by feature half:
//   G[p][node][f], p = j>>6, f = j&63   (two contiguous 12.8 MB halves)
// Computes G^T tiles: D = Wtile * h^T (A = W frag, B = h rows).
// C: lane l, reg r -> j = jt*16 + (l>>4)*4 + r, node = n0 + (l&15).
// ---------------------------------------------------------------------------
__global__ __launch_bounds__(256)
void gemm_G_kernel(const float* __restrict__ h,
                   const ushort_t* __restrict__ Wfrag,
                   ushort_t* __restrict__ G) {
    const int wave = threadIdx.x >> 6;
    const int l    = threadIdx.x & 63;
    const int tile = blockIdx.x * 4 + wave;
    if (tile >= N_NODES / 16) return;
    const int n0   = tile * 16;
    const int lrow = l & 15;
    const int lk   = l >> 4;

    union { short8 v; ushort_t u[8]; } bfrag[4];
    const float* hp = h + (size_t)(n0 + lrow) * D + lk * 8;
#pragma unroll
    for (int kt = 0; kt < 4; ++kt) {
        const float4 q0 = *reinterpret_cast<const float4*>(hp + kt * 32);
        const float4 q1 = *reinterpret_cast<const float4*>(hp + kt * 32 + 4);
        bfrag[kt].u[0] = (ushort_t)f2bf(q0.x);
        bfrag[kt].u[1] = (ushort_t)f2bf(q0.y);
        bfrag[kt].u[2] = (ushort_t)f2bf(q0.z);
        bfrag[kt].u[3] = (ushort_t)f2bf(q0.w);
        bfrag[kt].u[4] = (ushort_t)f2bf(q1.x);
        bfrag[kt].u[5] = (ushort_t)f2bf(q1.y);
        bfrag[kt].u[6] = (ushort_t)f2bf(q1.z);
        bfrag[kt].u[7] = (ushort_t)f2bf(q1.w);
    }

    const uint4* wf = reinterpret_cast<const uint4*>(Wfrag) + l;
#pragma unroll
    for (int jt = 0; jt < 8; ++jt) {
        f32x4 acc = {0.f, 0.f, 0.f, 0.f};
#pragma unroll
        for (int kt = 0; kt < 4; ++kt) {
            union { uint4 q; short8 v; } af;
            af.q = wf[(jt * 4 + kt) * 64];
            acc = __builtin_amdgcn_mfma_f32_16x16x32_bf16(af.v, bfrag[kt].v,
                                                          acc, 0, 0, 0);
        }
        uint2 o;
        o.x = f2bf(acc[0]) | (f2bf(acc[1]) << 16);
        o.y = f2bf(acc[2]) | (f2bf(acc[3]) << 16);
        const int p = jt >> 2;  // feature half
        ushort_t* dst = G + ((size_t)p * N_NODES + (n0 + lrow)) * 64 +
                        (jt & 3) * 16 + lk * 4;
        *reinterpret_cast<uint2*>(dst) = o;
    }
}

// ---------------------------------------------------------------------------
// Kernel 4: one feature-half pass of out = relu(S @ G + b).
// One node per 16-lane group; lane il owns 4 feats (8B bf16 -> uint2 loads,
// so a group's row = 128B = one cache line). Depth-8 edge unroll.
// Two sequential launches (pass 0, pass 1) keep the live G working set at
// 12.8 MB for better L2 hit rate.
// ---------------------------------------------------------------------------
__global__ __launch_bounds__(256)
void gconv_gather_half_kernel(const int* __restrict__ cols,
                              const float* __restrict__ vals,
                              const ushort_t* __restrict__ Gh,
                              const float* __restrict__ b,
                              const int* __restrict__ row_ptr,
                              float* __restrict__ out, int pass) {
    const int tid  = blockIdx.x * 256 + threadIdx.x;
    const int node = tid >> 4;
    const int il   = tid & 15;

    int e = row_ptr[node];
    const int end = row_ptr[node + 1];
    const ushort_t* gp = Gh + il * 4;

    float a0 = 0.f, a1 = 0.f, a2 = 0.f, a3 = 0.f;

    for (; e + 7 < end; e += 8) {
        const int c0 = cols[e];     const int c1 = cols[e + 1];
        const int c2 = cols[e + 2]; const int c3 = cols[e + 3];
        const int c4 = cols[e + 4]; const int c5 = cols[e + 5];
        const int c6 = cols[e + 6]; const int c7 = cols[e + 7];
        const float v0 = vals[e];     const float v1 = vals[e + 1];
        const float v2 = vals[e + 2]; const float v3 = vals[e + 3];
        const float v4 = vals[e + 4]; const float v5 = vals[e + 5];
        const float v6 = vals[e + 6]; const float v7 = vals[e + 7];
        const uint2 g0 = *reinterpret_cast<const uint2*>(gp + (size_t)c0 * 64);
        const uint2 g1 = *reinterpret_cast<const uint2*>(gp + (size_t)c1 * 64);
        const uint2 g2 = *reinterpret_cast<const uint2*>(gp + (size_t)c2 * 64);
        const uint2 g3 = *reinterpret_cast<const uint2*>(gp + (size_t)c3 * 64);
        const uint2 g4 = *reinterpret_cast<const uint2*>(gp + (size_t)c4 * 64);
        const uint2 g5 = *reinterpret_cast<const uint2*>(gp + (size_t)c5 * 64);
        const uint2 g6 = *reinterpret_cast<const uint2*>(gp + (size_t)c6 * 64);
        const uint2 g7 = *reinterpret_cast<const uint2*>(gp + (size_t)c7 * 64);
        a0 += v0 * __uint_as_float(g0.x << 16);
        a1 += v0 * __uint_as_float(g0.x & 0xffff0000u);
        a2 += v0 * __uint_as_float(g0.y << 16);
        a3 += v0 * __uint_as_float(g0.y & 0xffff0000u);
        a0 += v1 * __uint_as_float(g1.x << 16);
        a1 += v1 * __uint_as_float(g1.x & 0xffff0000u);
        a2 += v1 * __uint_as_float(g1.y << 16);
        a3 += v1 * __uint_as_float(g1.y & 0xffff0000u);
        a0 += v2 * __uint_as_float(g2.x << 16);
        a1 += v2 * __uint_as_float(g2.x & 0xffff0000u);
        a2 += v2 * __uint_as_float(g2.y << 16);
        a3 += v2 * __uint_as_float(g2.y & 0xffff0000u);
        a0 += v3 * __uint_as_float(g3.x << 16);
        a1 += v3 * __uint_as_float(g3.x & 0xffff0000u);
        a2 += v3 * __uint_as_float(g3.y << 16);
        a3 += v3 * __uint_as_float(g3.y & 0xffff0000u);
        a0 += v4 * __uint_as_float(g4.x << 16);
        a1 += v4 * __uint_as_float(g4.x & 0xffff0000u);
        a2 += v4 * __uint_as_float(g4.y << 16);
        a3 += v4 * __uint_as_float(g4.y & 0xffff0000u);
        a0 += v5 * __uint_as_float(g5.x << 16);
        a1 += v5 * __uint_as_float(g5.x & 0xffff0000u);
        a2 += v5 * __uint_as_float(g5.y << 16);
        a3 += v5 * __uint_as_float(g5.y & 0xffff0000u);
        a0 += v6 * __uint_as_float(g6.x << 16);
        a1 += v6 * __uint_as_float(g6.x & 0xffff0000u);
        a2 += v6 * __uint_as_float(g6.y << 16);
        a3 += v6 * __uint_as_float(g6.y & 0xffff0000u);
        a0 += v7 * __uint_as_float(g7.x << 16);
        a1 += v7 * __uint_as_float(g7.x & 0xffff0000u);
        a2 += v7 * __uint_as_float(g7.y << 16);
        a3 += v7 * __uint_as_float(g7.y & 0xffff0000u);
    }
    for (; e < end; ++e) {
        const int   c = cols[e];
        const float v = vals[e];
        const uint2 g = *reinterpret_cast<const uint2*>(gp + (size_t)c * 64);
        a0 += v * __uint_as_float(g.x << 16);
        a1 += v * __uint_as_float(g.x & 0xffff0000u);
        a2 += v * __uint_as_float(g.y << 16);
        a3 += v * __uint_as_float(g.y & 0xffff0000u);
    }

    const float4 bb = *reinterpret_cast<const float4*>(b + pass * 64 + il * 4);
    float4 r;
    r.x = a0 + bb.x; r.y = a1 + bb.y; r.z = a2 + bb.z; r.w = a3 + bb.w;
    r.x = r.x > 0.f ? r.x : 0.f;
    r.y = r.y > 0.f ? r.y : 0.f;
    r.z = r.z > 0.f ? r.z : 0.f;
    r.w = r.w > 0.f ? r.w : 0.f;
    *reinterpret_cast<float4*>(out + (size_t)node * D + pass * 64 + il * 4) = r;
}

// ---------------------------------------------------------------------------
extern "C" void kernel_launch(void* const* d_in, const int* in_sizes, int n_in,
                              void* d_out, int out_size, void* d_ws,
                              size_t ws_size, hipStream_t stream) {
    const int*   edge_rows = (const int*)d_in[0];
    const int*   edge_cols = (const int*)d_in[1];
    const float* edge_vals = (const float*)d_in[2];
    const float* h         = (const float*)d_in[3];
    const float* W         = (const float*)d_in[4];
    const float* b         = (const float*)d_in[5];
    float*       out       = (float*)d_out;

    const int n_edges = in_sizes[0];

    // workspace: [Wfrag 32KB][pad to 64KB][row_ptr 512KB][G split 25.6MB]
    ushort_t* Wfrag   = (ushort_t*)d_ws;
    int*      row_ptr = (int*)((char*)d_ws + 64 * 1024);
    ushort_t* G       = (ushort_t*)((char*)d_ws + 64 * 1024 + 512 * 1024);

    build_wfrag_kernel<<<32, 64, 0, stream>>>(W, Wfrag);

    const int rp_threads = 256;
    const int rp_blocks  = (N_NODES + 1 + rp_threads - 1) / rp_threads;
    build_rowptr_kernel<<<rp_blocks, rp_threads, 0, stream>>>(edge_rows,
                                                              row_ptr, n_edges);

    const int n_tiles = N_NODES / 16;  // 6250
    gemm_G_kernel<<<(n_tiles + 3) / 4, 256, 0, stream>>>(h, Wfrag, G);

    const int gather_blocks = N_NODES * 16 / 256;  // 6250
    const ushort_t* G0 = G;
    const ushort_t* G1 = G + (size_t)N_NODES * 64;
    gconv_gather_half_kernel<<<gather_blocks, 256, 0, stream>>>(
        edge_cols, edge_vals, G0, b, row_ptr, out, 0);
    gconv_gather_half_kernel<<<gather_blocks, 256, 0, stream>>>(
        edge_cols, edge_vals, G1, b, row_ptr, out, 1);
}

// Round 6
// 126.274 us; speedup vs baseline: 1.2374x; 1.2374x over previous
//
#include <hip/hip_runtime.h>

#define N_NODES 100000
#define D 128

typedef unsigned short ushort_t;
typedef unsigned char uchar_t;
typedef __attribute__((ext_vector_type(8))) short short8;
typedef __attribute__((ext_vector_type(4))) float f32x4;

// round-to-nearest-even f32 -> bf16 bits (finite inputs)
__device__ __forceinline__ unsigned f2bf(float x) {
    unsigned u = __float_as_uint(x);
    return (u + 0x7fffu + ((u >> 16) & 1u)) >> 16;
}

// ---------------------------------------------------------------------------
// Kernel 1: W -> MFMA A-fragment-ordered bf16 (Wfrag).
// mfma_f32_16x16x32_bf16 A-frag: lane l holds row (l&15), k = (l>>4)*8+i.
// A-matrix = W tile (jt,kt): A[j][k] = W[jt*16+j][kt*32+k].
// ---------------------------------------------------------------------------
__global__ __launch_bounds__(64)
void build_wfrag_kernel(const float* __restrict__ W,
                        ushort_t* __restrict__ Wfrag) {
    const int t  = blockIdx.x;      // 0..31 = jt*4 + kt
    const int jt = t >> 2, kt = t & 3;
    const int l  = threadIdx.x;
    const float* src = W + (size_t)(jt * 16 + (l & 15)) * D + kt * 32 + (l >> 4) * 8;
    const float4 p0 = *reinterpret_cast<const float4*>(src);
    const float4 p1 = *reinterpret_cast<const float4*>(src + 4);
    uint4 o;
    o.x = f2bf(p0.x) | (f2bf(p0.y) << 16);
    o.y = f2bf(p0.z) | (f2bf(p0.w) << 16);
    o.z = f2bf(p1.x) | (f2bf(p1.y) << 16);
    o.w = f2bf(p1.z) | (f2bf(p1.w) << 16);
    *reinterpret_cast<uint4*>(Wfrag + ((size_t)t * 64 + l) * 8) = o;
}

// ---------------------------------------------------------------------------
// Kernel 2: row_ptr[i] = lower_bound(edge_rows, i)
// ---------------------------------------------------------------------------
__global__ void build_rowptr_kernel(const int* __restrict__ rows,
                                    int* __restrict__ row_ptr, int n_edges) {
    int i = blockIdx.x * blockDim.x + threadIdx.x;
    if (i > N_NODES) return;
    int lo = 0, hi = n_edges;
    while (lo < hi) {
        int mid = (lo + hi) >> 1;
        if (rows[mid] < i) lo = mid + 1; else hi = mid;
    }
    row_ptr[i] = lo;
}

// ---------------------------------------------------------------------------
// Kernel 3q: G = H @ W^T via MFMA, quantized per-node to int8 (+128 bias):
//   Gq[node][j] = round(g / s) + 128,  s = scales[node] = rowmax|g| / 127.
// Row = 128 B = ONE cache line per edge in the gather.
// C frag: lane l, reg r -> j = jt*16 + (l>>4)*4 + r, node = n0 + (l&15).
// ---------------------------------------------------------------------------
__global__ __launch_bounds__(256)
void gemm_Gq_kernel(const float* __restrict__ h,
                    const ushort_t* __restrict__ Wfrag,
                    uchar_t* __restrict__ Gq,
                    float* __restrict__ scales) {
    const int wave = threadIdx.x >> 6;
    const int l    = threadIdx.x & 63;
    const int tile = blockIdx.x * 4 + wave;
    if (tile >= N_NODES / 16) return;
    const int n0   = tile * 16;
    const int lrow = l & 15;
    const int lk   = l >> 4;

    union { short8 v; ushort_t u[8]; } bfrag[4];
    const float* hp = h + (size_t)(n0 + lrow) * D + lk * 8;
#pragma unroll
    for (int kt = 0; kt < 4; ++kt) {
        const float4 q0 = *reinterpret_cast<const float4*>(hp + kt * 32);
        const float4 q1 = *reinterpret_cast<const float4*>(hp + kt * 32 + 4);
        bfrag[kt].u[0] = (ushort_t)f2bf(q0.x);
        bfrag[kt].u[1] = (ushort_t)f2bf(q0.y);
        bfrag[kt].u[2] = (ushort_t)f2bf(q0.z);
        bfrag[kt].u[3] = (ushort_t)f2bf(q0.w);
        bfrag[kt].u[4] = (ushort_t)f2bf(q1.x);
        bfrag[kt].u[5] = (ushort_t)f2bf(q1.y);
        bfrag[kt].u[6] = (ushort_t)f2bf(q1.z);
        bfrag[kt].u[7] = (ushort_t)f2bf(q1.w);
    }

    const uint4* wf = reinterpret_cast<const uint4*>(Wfrag) + l;
    f32x4 acc[8];
#pragma unroll
    for (int jt = 0; jt < 8; ++jt) {
        acc[jt] = (f32x4){0.f, 0.f, 0.f, 0.f};
#pragma unroll
        for (int kt = 0; kt < 4; ++kt) {
            union { uint4 q; short8 v; } af;
            af.q = wf[(jt * 4 + kt) * 64];
            acc[jt] = __builtin_amdgcn_mfma_f32_16x16x32_bf16(
                af.v, bfrag[kt].v, acc[jt], 0, 0, 0);
        }
    }

    // per-node amax over all 128 j (32 local values + lanes lrow,+16,+32,+48)
    float amax = 0.f;
#pragma unroll
    for (int jt = 0; jt < 8; ++jt) {
#pragma unroll
        for (int r = 0; r < 4; ++r) amax = fmaxf(amax, fabsf(acc[jt][r]));
    }
    amax = fmaxf(amax, __shfl_xor(amax, 16));
    amax = fmaxf(amax, __shfl_xor(amax, 32));
    const float s   = amax > 0.f ? amax * (1.f / 127.f) : 1.f;
    const float inv = amax > 0.f ? 127.f / amax : 0.f;

#pragma unroll
    for (int jt = 0; jt < 8; ++jt) {
        const unsigned q0 = (unsigned)((int)rintf(acc[jt][0] * inv) + 128);
        const unsigned q1 = (unsigned)((int)rintf(acc[jt][1] * inv) + 128);
        const unsigned q2 = (unsigned)((int)rintf(acc[jt][2] * inv) + 128);
        const unsigned q3 = (unsigned)((int)rintf(acc[jt][3] * inv) + 128);
        const unsigned pk = q0 | (q1 << 8) | (q2 << 16) | (q3 << 24);
        *reinterpret_cast<unsigned*>(
            Gq + (size_t)(n0 + lrow) * D + jt * 16 + lk * 4) = pk;
    }
    if (l < 16) scales[n0 + l] = s;
}

// ---------------------------------------------------------------------------
// Kernel 4q: vals2[e] = vals[e] * scales[cols[e]]  (scales is 400KB, L2-hot)
// ---------------------------------------------------------------------------
__global__ __launch_bounds__(256)
void fold_vals_kernel(const int* __restrict__ cols,
                      const float* __restrict__ vals,
                      const float* __restrict__ scales,
                      float* __restrict__ vals2, int n) {
    int i = blockIdx.x * 256 + threadIdx.x;
    if (i < n) vals2[i] = vals[i] * scales[cols[i]];
}

// ---------------------------------------------------------------------------
// Kernel 5q: out = relu(S @ dequant(Gq) + b). One node per 16-lane group;
// lane il owns feats il*8..il*8+7 (8 int8 = uint2 load; group row = 128B =
// ONE cache line per edge). out_f = sum v2*q_f - 128*sum v2 + b_f.
// ---------------------------------------------------------------------------
__device__ __forceinline__ void accq(float* a, float& vsum, float v, uint2 g) {
    a[0] += v * (float)(g.x & 0xffu);
    a[1] += v * (float)((g.x >> 8) & 0xffu);
    a[2] += v * (float)((g.x >> 16) & 0xffu);
    a[3] += v * (float)(g.x >> 24);
    a[4] += v * (float)(g.y & 0xffu);
    a[5] += v * (float)((g.y >> 8) & 0xffu);
    a[6] += v * (float)((g.y >> 16) & 0xffu);
    a[7] += v * (float)(g.y >> 24);
    vsum += v;
}

__global__ __launch_bounds__(256)
void gconv_gather_q_kernel(const int* __restrict__ cols,
                           const float* __restrict__ vals2,
                           const uchar_t* __restrict__ Gq,
                           const float* __restrict__ b,
                           const int* __restrict__ row_ptr,
                           float* __restrict__ out) {
    const int tid  = blockIdx.x * 256 + threadIdx.x;
    const int node = tid >> 4;
    const int il   = tid & 15;

    int e = row_ptr[node];
    const int end = row_ptr[node + 1];
    const uchar_t* gp = Gq + il * 8;

    float a[8];
#pragma unroll
    for (int j = 0; j < 8; ++j) a[j] = 0.f;
    float vsum = 0.f;

    for (; e + 7 < end; e += 8) {
        int   c[8];
        float v[8];
        uint2 g[8];
#pragma unroll
        for (int i = 0; i < 8; ++i) c[i] = cols[e + i];
#pragma unroll
        for (int i = 0; i < 8; ++i) v[i] = vals2[e + i];
#pragma unroll
        for (int i = 0; i < 8; ++i)
            g[i] = *reinterpret_cast<const uint2*>(gp + (size_t)c[i] * D);
#pragma unroll
        for (int i = 0; i < 8; ++i) accq(a, vsum, v[i], g[i]);
    }
    for (; e < end; ++e) {
        const int   c = cols[e];
        const float v = vals2[e];
        const uint2 g = *reinterpret_cast<const uint2*>(gp + (size_t)c * D);
        accq(a, vsum, v, g);
    }

    const float4 b0 = *reinterpret_cast<const float4*>(b + il * 8);
    const float4 b1 = *reinterpret_cast<const float4*>(b + il * 8 + 4);
    const float corr = 128.f * vsum;
    float4 r0, r1;
    r0.x = a[0] - corr + b0.x; r0.y = a[1] - corr + b0.y;
    r0.z = a[2] - corr + b0.z; r0.w = a[3] - corr + b0.w;
    r1.x = a[4] - corr + b1.x; r1.y = a[5] - corr + b1.y;
    r1.z = a[6] - corr + b1.z; r1.w = a[7] - corr + b1.w;
    r0.x = r0.x > 0.f ? r0.x : 0.f;
    r0.y = r0.y > 0.f ? r0.y : 0.f;
    r0.z = r0.z > 0.f ? r0.z : 0.f;
    r0.w = r0.w > 0.f ? r0.w : 0.f;
    r1.x = r1.x > 0.f ? r1.x : 0.f;
    r1.y = r1.y > 0.f ? r1.y : 0.f;
    r1.z = r1.z > 0.f ? r1.z : 0.f;
    r1.w = r1.w > 0.f ? r1.w : 0.f;
    float* op = out + (size_t)node * D + il * 8;
    *reinterpret_cast<float4*>(op)     = r0;
    *reinterpret_cast<float4*>(op + 4) = r1;
}

// ---------------------------------------------------------------------------
// Fallback path (proven R4): bf16 G, 2 lines/edge. Used if ws too small.
// ---------------------------------------------------------------------------
__global__ __launch_bounds__(256)
void gemm_G_kernel(const float* __restrict__ h,
                   const ushort_t* __restrict__ Wfrag,
                   ushort_t* __restrict__ G) {
    const int wave = threadIdx.x >> 6;
    const int l    = threadIdx.x & 63;
    const int tile = blockIdx.x * 4 + wave;
    if (tile >= N_NODES / 16) return;
    const int n0   = tile * 16;
    const int lrow = l & 15;
    const int lk   = l >> 4;

    union { short8 v; ushort_t u[8]; } bfrag[4];
    const float* hp = h + (size_t)(n0 + lrow) * D + lk * 8;
#pragma unroll
    for (int kt = 0; kt < 4; ++kt) {
        const float4 q0 = *reinterpret_cast<const float4*>(hp + kt * 32);
        const float4 q1 = *reinterpret_cast<const float4*>(hp + kt * 32 + 4);
        bfrag[kt].u[0] = (ushort_t)f2bf(q0.x);
        bfrag[kt].u[1] = (ushort_t)f2bf(q0.y);
        bfrag[kt].u[2] = (ushort_t)f2bf(q0.z);
        bfrag[kt].u[3] = (ushort_t)f2bf(q0.w);
        bfrag[kt].u[4] = (ushort_t)f2bf(q1.x);
        bfrag[kt].u[5] = (ushort_t)f2bf(q1.y);
        bfrag[kt].u[6] = (ushort_t)f2bf(q1.z);
        bfrag[kt].u[7] = (ushort_t)f2bf(q1.w);
    }

    const uint4* wf = reinterpret_cast<const uint4*>(Wfrag) + l;
#pragma unroll
    for (int jt = 0; jt < 8; ++jt) {
        f32x4 acc = {0.f, 0.f, 0.f, 0.f};
#pragma unroll
        for (int kt = 0; kt < 4; ++kt) {
            union { uint4 q; short8 v; } af;
            af.q = wf[(jt * 4 + kt) * 64];
            acc = __builtin_amdgcn_mfma_f32_16x16x32_bf16(af.v, bfrag[kt].v,
                                                          acc, 0, 0, 0);
        }
        uint2 o;
        o.x = f2bf(acc[0]) | (f2bf(acc[1]) << 16);
        o.y = f2bf(acc[2]) | (f2bf(acc[3]) << 16);
        *reinterpret_cast<uint2*>(G + (size_t)(n0 + lrow) * D + jt * 16 + lk * 4) = o;
    }
}

__device__ __forceinline__ void acc8(float2& a0, float2& a1, float2& a2,
                                     float2& a3, float v, uint4 g) {
    a0.x += v * __uint_as_float(g.x << 16);
    a0.y += v * __uint_as_float(g.x & 0xffff0000u);
    a1.x += v * __uint_as_float(g.y << 16);
    a1.y += v * __uint_as_float(g.y & 0xffff0000u);
    a2.x += v * __uint_as_float(g.z << 16);
    a2.y += v * __uint_as_float(g.z & 0xffff0000u);
    a3.x += v * __uint_as_float(g.w << 16);
    a3.y += v * __uint_as_float(g.w & 0xffff0000u);
}

__global__ __launch_bounds__(256)
void gconv_gather_kernel(const int* __restrict__ cols,
                         const float* __restrict__ vals,
                         const ushort_t* __restrict__ G,
                         const float* __restrict__ b,
                         const int* __restrict__ row_ptr,
                         float* __restrict__ out) {
    const int tid  = blockIdx.x * 256 + threadIdx.x;
    const int node = tid >> 4;
    const int il   = tid & 15;

    int e = row_ptr[node];
    const int end = row_ptr[node + 1];
    const ushort_t* gp = G + il * 8;

    float2 a0 = make_float2(0.f, 0.f), a1 = make_float2(0.f, 0.f);
    float2 a2 = make_float2(0.f, 0.f), a3 = make_float2(0.f, 0.f);

    for (; e + 3 < end; e += 4) {
        const int c0 = cols[e];
        const int c1 = cols[e + 1];
        const int c2 = cols[e + 2];
        const int c3 = cols[e + 3];
        const float v0 = vals[e];
        const float v1 = vals[e + 1];
        const float v2 = vals[e + 2];
        const float v3 = vals[e + 3];
        const uint4 g0 = *reinterpret_cast<const uint4*>(gp + (size_t)c0 * D);
        const uint4 g1 = *reinterpret_cast<const uint4*>(gp + (size_t)c1 * D);
        const uint4 g2 = *reinterpret_cast<const uint4*>(gp + (size_t)c2 * D);
        const uint4 g3 = *reinterpret_cast<const uint4*>(gp + (size_t)c3 * D);
        acc8(a0, a1, a2, a3, v0, g0);
        acc8(a0, a1, a2, a3, v1, g1);
        acc8(a0, a1, a2, a3, v2, g2);
        acc8(a0, a1, a2, a3, v3, g3);
    }
    for (; e < end; ++e) {
        const uint4 g = *reinterpret_cast<const uint4*>(gp + (size_t)cols[e] * D);
        acc8(a0, a1, a2, a3, vals[e], g);
    }

    const float4 b0 = *reinterpret_cast<const float4*>(b + il * 8);
    const float4 b1 = *reinterpret_cast<const float4*>(b + il * 8 + 4);
    float4 r0, r1;
    r0.x = a0.x + b0.x; r0.y = a0.y + b0.y;
    r0.z = a1.x + b0.z; r0.w = a1.y + b0.w;
    r1.x = a2.x + b1.x; r1.y = a2.y + b1.y;
    r1.z = a3.x + b1.z; r1.w = a3.y + b1.w;
    r0.x = r0.x > 0.f ? r0.x : 0.f;
    r0.y = r0.y > 0.f ? r0.y : 0.f;
    r0.z = r0.z > 0.f ? r0.z : 0.f;
    r0.w = r0.w > 0.f ? r0.w : 0.f;
    r1.x = r1.x > 0.f ? r1.x : 0.f;
    r1.y = r1.y > 0.f ? r1.y : 0.f;
    r1.z = r1.z > 0.f ? r1.z : 0.f;
    r1.w = r1.w > 0.f ? r1.w : 0.f;
    float* op = out + (size_t)node * D + il * 8;
    *reinterpret_cast<float4*>(op)     = r0;
    *reinterpret_cast<float4*>(op + 4) = r1;
}

// ---------------------------------------------------------------------------
extern "C" void kernel_launch(void* const* d_in, const int* in_sizes, int n_in,
                              void* d_out, int out_size, void* d_ws,
                              size_t ws_size, hipStream_t stream) {
    const int*   edge_rows = (const int*)d_in[0];
    const int*   edge_cols = (const int*)d_in[1];
    const float* edge_vals = (const float*)d_in[2];
    const float* h         = (const float*)d_in[3];
    const float* W         = (const float*)d_in[4];
    const float* b         = (const float*)d_in[5];
    float*       out       = (float*)d_out;

    const int n_edges = in_sizes[0];

    // q-path layout: [Wfrag 32K|pad][row_ptr 400K|pad][scales 400K|pad]
    //                [Gq 12.8M][vals2 12.8M]
    const size_t OFF_RP = 64 * 1024;
    const size_t OFF_SC = OFF_RP + 512 * 1024;
    const size_t OFF_GQ = OFF_SC + 512 * 1024;
    const size_t OFF_V2 = OFF_GQ + (size_t)N_NODES * D;
    const size_t need_q = OFF_V2 + (size_t)n_edges * sizeof(float);

    ushort_t* Wfrag   = (ushort_t*)d_ws;
    int*      row_ptr = (int*)((char*)d_ws + OFF_RP);

    build_wfrag_kernel<<<32, 64, 0, stream>>>(W, Wfrag);

    const int rp_threads = 256;
    const int rp_blocks  = (N_NODES + 1 + rp_threads - 1) / rp_threads;
    build_rowptr_kernel<<<rp_blocks, rp_threads, 0, stream>>>(edge_rows,
                                                              row_ptr, n_edges);

    const int n_tiles       = N_NODES / 16;        // 6250
    const int gemm_blocks   = (n_tiles + 3) / 4;
    const int gather_blocks = N_NODES * 16 / 256;  // 6250

    if (ws_size >= need_q) {
        float*   scales = (float*)((char*)d_ws + OFF_SC);
        uchar_t* Gq     = (uchar_t*)((char*)d_ws + OFF_GQ);
        float*   vals2  = (float*)((char*)d_ws + OFF_V2);

        gemm_Gq_kernel<<<gemm_blocks, 256, 0, stream>>>(h, Wfrag, Gq, scales);
        fold_vals_kernel<<<(n_edges + 255) / 256, 256, 0, stream>>>(
            edge_cols, edge_vals, scales, vals2, n_edges);
        gconv_gather_q_kernel<<<gather_blocks, 256, 0, stream>>>(
            edge_cols, vals2, Gq, b, row_ptr, out);
    } else {
        // fallback: bf16 G (26.2 MB), proven R4 path
        ushort_t* G = (ushort_t*)((char*)d_ws + OFF_SC);
        gemm_G_kernel<<<gemm_blocks, 256, 0, stream>>>(h, Wfrag, G);
        gconv_gather_kernel<<<gather_blocks, 256, 0, stream>>>(
            edge_cols, edge_vals, G, b, row_ptr, out);
    }
}